// Round 14
// baseline (25.891 us; speedup 1.0000x reference)
//
#include <hip/hip_runtime.h>

#define DD 128
#define HH 160
#define WW 128
#define BB 4
#define HW  20480
#define DHW 2621440

#define TX 32
#define TY 8
#define TZ 8
#define XT 4                     // WW/TX
#define YT 20                    // HH/TY
#define ZT 16                    // DD/TZ
#define NWG (XT * YT * ZT * BB)  // 5120
#define NXCD 8
#define CPX (NWG / NXCD)         // 640

// fixed-shape LDS window (compile-time strides -> immediate DS offsets)
#define FZE   14
#define FYE   14
#define PITCH 44                 // floats per row
#define SLABF (FYE * PITCH)      // 616 floats per z-slab
#define ROWB  (PITCH * 4)        // 176 B
#define SLABB (SLABF * 4)        // 2464 B
#define SLABCH (FYE * 11)        // 154 chunks per slab
#define NIT 9                    // staging vmem instrs (FIXED for counted vmcnt)
#define LDSALLOC (NIT * 1024)    // 9216 floats = 36864 B -> 4 blocks/CU

typedef float f2 __attribute__((ext_vector_type(2), aligned(4)));
typedef float v2 __attribute__((ext_vector_type(2)));

__global__ __launch_bounds__(256)
void st_affine_kernel(const float* __restrict__ src,
                      const float* __restrict__ aff,
                      float* __restrict__ out) {
    __shared__ float lds[LDSALLOC];

    // XCD-aware bijective swizzle (NWG % 8 == 0)
    const int wgid = blockIdx.x;
    const int lin  = (wgid & (NXCD - 1)) * CPX + (wgid >> 3);
    const int xt = lin & 3;
    const int l2 = lin >> 2;
    const int yt = l2 % YT;
    const int l3 = l2 / YT;
    const int zt = l3 & (ZT - 1);
    const int b  = l3 >> 4;
    const int x0t = xt * TX, y0t = yt * TY, z0t = zt * TZ;

    const float* A = aff + b * 12;   // uniform -> scalar loads
    const float cD = 128.f/127.f, cH = 160.f/159.f, cW = 128.f/127.f;
    const float pz0 = A[0]*cD, pz1 = A[1]*cD, pz2 = A[2]*cD,  pz3 = fmaf(A[3],  cD, -0.5f);
    const float py0 = A[4]*cH, py1 = A[5]*cH, py2 = A[6]*cH,  py3 = fmaf(A[7],  cH, -0.5f);
    const float px0 = A[8]*cW, px1 = A[9]*cW, px2 = A[10]*cW, px3 = fmaf(A[11], cW, -0.5f);

    // ---- bbox via center +- sum(|coef|*halfext) ----
    const float hz = (TZ - 1) * 0.5f, hy = (TY - 1) * 0.5f, hx = (TX - 1) * 0.5f;
    const float ccz = (float)z0t + hz, ccy = (float)y0t + hy, ccx = (float)x0t + hx;
    const float izcn = fmaf(pz0, ccz, fmaf(pz1, ccy, fmaf(pz2, ccx, pz3)));
    const float iycn = fmaf(py0, ccz, fmaf(py1, ccy, fmaf(py2, ccx, py3)));
    const float ixcn = fmaf(px0, ccz, fmaf(px1, ccy, fmaf(px2, ccx, px3)));
    const float rz = fmaf(fabsf(pz0), hz, fmaf(fabsf(pz1), hy, fmaf(fabsf(pz2), hx, 1e-3f)));
    const float ry = fmaf(fabsf(py0), hz, fmaf(fabsf(py1), hy, fmaf(fabsf(py2), hx, 1e-3f)));
    const float rx = fmaf(fabsf(px0), hz, fmaf(fabsf(px1), hy, fmaf(fabsf(px2), hx, 1e-3f)));
    const float mnz = izcn - rz, mxz = izcn + rz;
    const float mny = iycn - ry, mxy = iycn + ry;
    const float mnx = ixcn - rx, mxx = ixcn + rx;

    const bool interior =
        (mnz > 0.02f) && (mxz < 126.98f) &&
        (mny > 0.02f) && (mxy < 158.98f) &&
        (mnx > 0.02f) && (mxx < 126.98f);

    const int xlo = max(0, (int)floorf(__builtin_amdgcn_fmed3f(mnx, 0.f, 127.f)) - 1);
    const int ylo = max(0, (int)floorf(__builtin_amdgcn_fmed3f(mny, 0.f, 159.f)) - 1);
    const int zlo = max(0, (int)floorf(__builtin_amdgcn_fmed3f(mnz, 0.f, 127.f)) - 1);
    const int xhi = min(WW - 2, (int)floorf(__builtin_amdgcn_fmed3f(mxx, 0.f, 127.f)) + 1);
    const int yhi = min(HH - 2, (int)floorf(__builtin_amdgcn_fmed3f(mxy, 0.f, 159.f)) + 1);
    const int zhi = min(DD - 2, (int)floorf(__builtin_amdgcn_fmed3f(mxz, 0.f, 127.f)) + 1);

    const int xlo4 = xlo & ~3;
    const int XE4  = xhi - xlo4 + 2;
    const int YE   = yhi - ylo + 2;
    const int ZE   = zhi - zlo + 2;
    const bool fits = (XE4 <= PITCH) && (YE <= FYE) && (ZE <= FZE);

    const float zloF = (float)zlo, yloF = (float)ylo, xlo4F = (float)xlo4;

    // phase split legality: outputs with z-offset d in {0..3} (sub-box center
    // z0t+1.5, halfext 1.5) must have cell base <= zlo+7 (slabs 0..8 = the
    // data covered by the first 6 of 9 staging instructions: 6*256=1536 >=
    // 9*154=1386 chunks). Bbox of the sub-box gives the exact bound.
    const float izs1max = fmaf(pz0, (float)z0t + 1.5f,
                               fmaf(pz1, ccy, fmaf(pz2, ccx, pz3)))
                        + fmaf(fabsf(pz0), 1.5f,
                               fmaf(fabsf(pz1), hy, fmaf(fabsf(pz2), hx, 1e-3f)));
    const bool splitOK = fits && (izs1max < zloF + 7.5f);

    const int tid  = threadIdx.x;
    const int lane = tid & 63;
    const int wid  = tid >> 6;

    // outputs: x-pair, y per (lane,wid), z-chain 0,1 then 4,5 offsets from zb
    const int xp = x0t + ((lane & 15) << 1);
    const int yo = y0t + (lane >> 4) + ((wid & 1) << 2);
    const int zb = z0t + ((wid >> 1) << 1);          // waves: z0t or z0t+2
    const float fx0 = (float)xp, fy = (float)yo, fzb = (float)zb;

    const float izb0 = fmaf(pz0, fzb, fmaf(pz1, fy, fmaf(pz2, fx0, pz3)));
    const float iyb0 = fmaf(py0, fzb, fmaf(py1, fy, fmaf(py2, fx0, py3)));
    const float ixb0 = fmaf(px0, fzb, fmaf(px1, fy, fmaf(px2, fx0, px3)));

    const float* sb = src + b * DHW;
    float* dst0 = out + (size_t)(((b * DD + zb) * HH + yo) * WW + xp);

    // ---- dense full-wave staging into fixed-shape window: EXACTLY NIT instrs ----
    if (fits) {
        const float RC154 = 1.f / 154.f, RC11 = 1.f / 11.f;
        const float gbase = fmaf(zloF, 20480.f, fmaf(yloF, 128.f, xlo4F)); // exact
#pragma unroll
        for (int it = 0; it < NIT; ++it) {
            const int k = (it << 8) + tid;
            float kf  = (float)k;                                // overshoot chunks:
            float zif = floorf(fmaf(kf, RC154, 0.5f * RC154));   // clamped addr, land
            float rem = fmaf(zif, -154.f, kf);                   // in unused LDS
            float yif = floorf(fmaf(rem, RC11, 0.5f * RC11));
            float xif = fmaf(yif, -11.f, rem);
            float gf  = fmaf(zif, 20480.f, fmaf(yif, 128.f, fmaf(xif, 4.f, gbase)));
            int g = min((int)gf, DHW - 4);                       // tail guard
            __builtin_amdgcn_global_load_lds(
                (const __attribute__((address_space(1))) void*)(sb + g),
                (__attribute__((address_space(3))) void*)(lds + (size_t)(((it << 8) + (wid << 6)) * 4)),
                16, 0, 0);
        }
    }

    const char* Lb = (const char*)lds;

    // packed trilinear from LDS (byte offsets, compile-time strides)
    auto triL = [&](int o0, int o1, v2 wx, v2 wy, v2 wz) -> v2 {
        f2 a00 = *(const f2*)(Lb + o0);
        f2 a01 = *(const f2*)(Lb + o0 + ROWB);
        f2 a10 = *(const f2*)(Lb + o0 + SLABB);
        f2 a11 = *(const f2*)(Lb + o0 + SLABB + ROWB);
        f2 b00 = *(const f2*)(Lb + o1);
        f2 b01 = *(const f2*)(Lb + o1 + ROWB);
        f2 b10 = *(const f2*)(Lb + o1 + SLABB);
        f2 b11 = *(const f2*)(Lb + o1 + SLABB + ROWB);
        v2 c00 = {fmaf(a00.y - a00.x, wx.x, a00.x), fmaf(b00.y - b00.x, wx.y, b00.x)};
        v2 c01 = {fmaf(a01.y - a01.x, wx.x, a01.x), fmaf(b01.y - b01.x, wx.y, b01.x)};
        v2 c10 = {fmaf(a10.y - a10.x, wx.x, a10.x), fmaf(b10.y - b10.x, wx.y, b10.x)};
        v2 c11 = {fmaf(a11.y - a11.x, wx.x, a11.x), fmaf(b11.y - b11.x, wx.y, b11.x)};
        v2 c0 = c00 + (c01 - c00) * wy;
        v2 c1 = c10 + (c11 - c10) * wy;
        return c0 + (c1 - c0) * wz;
    };

    if (fits) {
        const v2 dzv = {pz0, pz0}, dyv = {py0, py0}, dxv = {px0, px0};
        const float hiZ = 127.f - zloF, capZ = 126.f - zloF;
        const float hiY = 159.f - yloF, capY = 158.f - yloF;
        const float hiX = 127.f - xlo4F, capX = 126.f - xlo4F;

        // relative coords (exact: lo's are integers -> floor commutes)
        v2 az = {izb0 - zloF, izb0 + pz2 - zloF};
        v2 ay = {iyb0 - yloF, iyb0 + py2 - yloF};
        v2 ax = {ixb0 - xlo4F, ixb0 + px2 - xlo4F};

        auto doPair = [&](float* d) {
            v2 cz, cy, cx, wz, wy, wx;
            if (interior) {
                cz = v2{floorf(az.x), floorf(az.y)};
                cy = v2{floorf(ay.x), floorf(ay.y)};
                cx = v2{floorf(ax.x), floorf(ax.y)};
                wz = az - cz; wy = ay - cy; wx = ax - cx;
            } else {
                v2 azc = {__builtin_amdgcn_fmed3f(az.x, 0.f, hiZ),
                          __builtin_amdgcn_fmed3f(az.y, 0.f, hiZ)};
                v2 ayc = {__builtin_amdgcn_fmed3f(ay.x, 0.f, hiY),
                          __builtin_amdgcn_fmed3f(ay.y, 0.f, hiY)};
                v2 axc = {__builtin_amdgcn_fmed3f(ax.x, 0.f, hiX),
                          __builtin_amdgcn_fmed3f(ax.y, 0.f, hiX)};
                cz = v2{fminf(floorf(azc.x), capZ), fminf(floorf(azc.y), capZ)};
                cy = v2{fminf(floorf(ayc.x), capY), fminf(floorf(ayc.y), capY)};
                cx = v2{fminf(floorf(axc.x), capX), fminf(floorf(axc.y), capX)};
                wz = azc - cz; wy = ayc - cy; wx = axc - cx;
            }
            v2 ob = (cz * (float)FYE + cy) * (float)ROWB + cx * 4.f;  // bytes, exact
            v2 r = triL((int)ob.x, (int)ob.y, wx, wy, wz);
            __builtin_nontemporal_store(r, (v2*)d);
        };
        auto adv = [&]() { az += dzv; ay += dyv; ax += dxv; };

        // ---- phase 1: z-offsets 0,1 (cells in slabs 0..8 when splitOK) ----
        if (splitOK) {
            asm volatile("s_waitcnt vmcnt(3)" ::: "memory");  // first 6 of 9 landed
        } else {
            asm volatile("s_waitcnt vmcnt(0)" ::: "memory");
        }
        __builtin_amdgcn_s_barrier();
        __builtin_amdgcn_sched_barrier(0);

        doPair(dst0);
        adv();
        doPair(dst0 + HW);

        // ---- phase 2: z-offsets 4,5; last 3 stage loads are the oldest
        // outstanding vmem (phase-1's 2 stores are newer) -> vmcnt(2) ----
        asm volatile("s_waitcnt vmcnt(2)" ::: "memory");
        __builtin_amdgcn_s_barrier();
        __builtin_amdgcn_sched_barrier(0);

        adv(); adv(); adv();               // advance z-offset 1 -> 4
        doPair(dst0 + 4 * HW);
        adv();
        doPair(dst0 + 5 * HW);
    } else {
        // direct-gather fallback (rare, >=3.8-sigma affine entry; no barriers,
        // block-uniform branch; same math)
        v2 az = {izb0, izb0 + pz2};
        v2 ay = {iyb0, iyb0 + py2};
        v2 ax = {ixb0, ixb0 + px2};
        const v2 dzv = {pz0, pz0}, dyv = {py0, py0}, dxv = {px0, px0};
        const int zoffs[4] = {0, 1, 4, 5};
#pragma unroll
        for (int s = 0; s < 4; ++s) {
            v2 azc = {__builtin_amdgcn_fmed3f(az.x, 0.f, 127.f),
                      __builtin_amdgcn_fmed3f(az.y, 0.f, 127.f)};
            v2 ayc = {__builtin_amdgcn_fmed3f(ay.x, 0.f, 159.f),
                      __builtin_amdgcn_fmed3f(ay.y, 0.f, 159.f)};
            v2 axc = {__builtin_amdgcn_fmed3f(ax.x, 0.f, 127.f),
                      __builtin_amdgcn_fmed3f(ax.y, 0.f, 127.f)};
            v2 cz = {fminf(floorf(azc.x), 126.f), fminf(floorf(azc.y), 126.f)};
            v2 cy = {fminf(floorf(ayc.x), 158.f), fminf(floorf(ayc.y), 158.f)};
            v2 cx = {fminf(floorf(axc.x), 126.f), fminf(floorf(axc.y), 126.f)};
            v2 wz = azc - cz, wy = ayc - cy, wx = axc - cx;
            auto g1 = [&](float czs, float cys, float cxs, float wxs, float wys, float wzs) -> float {
                int o = (int)fmaf(czs, 20480.f, fmaf(cys, 128.f, cxs));
                const float* p = sb + o;
                f2 v00 = *(const f2*)(p);
                f2 v01 = *(const f2*)(p + WW);
                f2 v10 = *(const f2*)(p + HW);
                f2 v11 = *(const f2*)(p + HW + WW);
                float c00 = fmaf(v00.y - v00.x, wxs, v00.x);
                float c01 = fmaf(v01.y - v01.x, wxs, v01.x);
                float c10 = fmaf(v10.y - v10.x, wxs, v10.x);
                float c11 = fmaf(v11.y - v11.x, wxs, v11.x);
                float c0 = fmaf(c01 - c00, wys, c00);
                float c1 = fmaf(c11 - c10, wys, c10);
                return fmaf(c1 - c0, wzs, c0);
            };
            v2 r;
            r.x = g1(cz.x, cy.x, cx.x, wx.x, wy.x, wz.x);
            r.y = g1(cz.y, cy.y, cx.y, wx.y, wy.y, wz.y);
            __builtin_nontemporal_store(r, (v2*)(dst0 + zoffs[s] * HW));
            // advance to next z-offset in {0,1,4,5}
            if (s == 1) { az += dzv; ay += dyv; ax += dxv;
                          az += dzv; ay += dyv; ax += dxv; }
            az += dzv; ay += dyv; ax += dxv;
        }
    }
}

extern "C" void kernel_launch(void* const* d_in, const int* in_sizes, int n_in,
                              void* d_out, int out_size, void* d_ws, size_t ws_size,
                              hipStream_t stream) {
    const float* src = (const float*)d_in[0];
    const float* aff = (const float*)d_in[1];
    float* out = (float*)d_out;

    st_affine_kernel<<<dim3(NWG), dim3(256), 0, stream>>>(src, aff, out);
}

// Round 15
// 24.938 us; speedup vs baseline: 1.0382x; 1.0382x over previous
//
#include <hip/hip_runtime.h>

#define DD 128
#define HH 160
#define WW 128
#define BB 4
#define HW  20480
#define DHW 2621440

#define TX 32
#define TY 8
#define TZ 8
#define XT 4                     // WW/TX
#define YT 20                    // HH/TY
#define ZT 16                    // DD/TZ
#define NWG (XT * YT * ZT * BB)  // 5120
#define NXCD 8
#define CPX (NWG / NXCD)         // 640

// fixed-shape LDS window (compile-time strides -> immediate DS offsets)
#define FZE   14
#define FYE   14
#define PITCH 44                 // floats per row
#define SLABF (FYE * PITCH)      // 616 floats per z-slab
#define ROWB  (PITCH * 4)        // 176 B
#define SLABB (SLABF * 4)        // 2464 B
#define NIT 9                    // staging vmem instrs
#define LDSALLOC (NIT * 1024)    // 9216 floats = 36864 B -> 4 blocks/CU

typedef float f2 __attribute__((ext_vector_type(2), aligned(4)));
typedef float v2 __attribute__((ext_vector_type(2)));

__global__ __launch_bounds__(256)
void st_affine_kernel(const float* __restrict__ src,
                      const float* __restrict__ aff,
                      float* __restrict__ out) {
    __shared__ float lds[LDSALLOC];

    // XCD-aware bijective swizzle (NWG % 8 == 0)
    const int wgid = blockIdx.x;
    const int lin  = (wgid & (NXCD - 1)) * CPX + (wgid >> 3);
    const int xt = lin & 3;
    const int l2 = lin >> 2;
    const int yt = l2 % YT;
    const int l3 = l2 / YT;
    const int zt = l3 & (ZT - 1);
    const int b  = l3 >> 4;
    const int x0t = xt * TX, y0t = yt * TY, z0t = zt * TZ;

    const float* A = aff + b * 12;   // uniform -> scalar loads
    const float cD = 128.f/127.f, cH = 160.f/159.f, cW = 128.f/127.f;
    const float pz0 = A[0]*cD, pz1 = A[1]*cD, pz2 = A[2]*cD,  pz3 = fmaf(A[3],  cD, -0.5f);
    const float py0 = A[4]*cH, py1 = A[5]*cH, py2 = A[6]*cH,  py3 = fmaf(A[7],  cH, -0.5f);
    const float px0 = A[8]*cW, px1 = A[9]*cW, px2 = A[10]*cW, px3 = fmaf(A[11], cW, -0.5f);

    // ---- bbox via center +- sum(|coef|*halfext) ----
    const float hz = (TZ - 1) * 0.5f, hy = (TY - 1) * 0.5f, hx = (TX - 1) * 0.5f;
    const float ccz = (float)z0t + hz, ccy = (float)y0t + hy, ccx = (float)x0t + hx;
    const float izcn = fmaf(pz0, ccz, fmaf(pz1, ccy, fmaf(pz2, ccx, pz3)));
    const float iycn = fmaf(py0, ccz, fmaf(py1, ccy, fmaf(py2, ccx, py3)));
    const float ixcn = fmaf(px0, ccz, fmaf(px1, ccy, fmaf(px2, ccx, px3)));
    const float rz = fmaf(fabsf(pz0), hz, fmaf(fabsf(pz1), hy, fmaf(fabsf(pz2), hx, 1e-3f)));
    const float ry = fmaf(fabsf(py0), hz, fmaf(fabsf(py1), hy, fmaf(fabsf(py2), hx, 1e-3f)));
    const float rx = fmaf(fabsf(px0), hz, fmaf(fabsf(px1), hy, fmaf(fabsf(px2), hx, 1e-3f)));
    const float mnz = izcn - rz, mxz = izcn + rz;
    const float mny = iycn - ry, mxy = iycn + ry;
    const float mnx = ixcn - rx, mxx = ixcn + rx;

    const bool interior =
        (mnz > 0.02f) && (mxz < 126.98f) &&
        (mny > 0.02f) && (mxy < 158.98f) &&
        (mnx > 0.02f) && (mxx < 126.98f);

    const int xlo = max(0, (int)floorf(__builtin_amdgcn_fmed3f(mnx, 0.f, 127.f)) - 1);
    const int ylo = max(0, (int)floorf(__builtin_amdgcn_fmed3f(mny, 0.f, 159.f)) - 1);
    const int zlo = max(0, (int)floorf(__builtin_amdgcn_fmed3f(mnz, 0.f, 127.f)) - 1);
    const int xhi = min(WW - 2, (int)floorf(__builtin_amdgcn_fmed3f(mxx, 0.f, 127.f)) + 1);
    const int yhi = min(HH - 2, (int)floorf(__builtin_amdgcn_fmed3f(mxy, 0.f, 159.f)) + 1);
    const int zhi = min(DD - 2, (int)floorf(__builtin_amdgcn_fmed3f(mxz, 0.f, 127.f)) + 1);

    const int xlo4 = xlo & ~3;
    const int XE4  = xhi - xlo4 + 2;
    const int YE   = yhi - ylo + 2;
    const int ZE   = zhi - zlo + 2;
    const bool fits = (XE4 <= PITCH) && (YE <= FYE) && (ZE <= FZE);

    const float zloF = (float)zlo, yloF = (float)ylo, xlo4F = (float)xlo4;

    const int tid  = threadIdx.x;
    const int lane = tid & 63;
    const int wid  = tid >> 6;

    // ---- outputs: ONE x per thread (stride-1 across 32 lanes -> LDS reads
    // spread over all 32 banks, ~2 lanes/bank = conflict-free), 8-z chain ----
    const int xq = x0t + (lane & 31);
    const int yo = y0t + (lane >> 5) + (wid << 1);
    const float fx0 = (float)xq, fy = (float)yo, fzb = (float)z0t;

    const float izb0 = fmaf(pz0, fzb, fmaf(pz1, fy, fmaf(pz2, fx0, pz3)));
    const float iyb0 = fmaf(py0, fzb, fmaf(py1, fy, fmaf(py2, fx0, py3)));
    const float ixb0 = fmaf(px0, fzb, fmaf(px1, fy, fmaf(px2, fx0, px3)));

    const float* sb = src + b * DHW;
    float* dst0 = out + (size_t)(((b * DD + z0t) * HH + yo) * WW + xq);

    // ---- dense full-wave staging into fixed-shape window ----
    if (fits) {
        const float RC154 = 1.f / 154.f, RC11 = 1.f / 11.f;
        const float gbase = fmaf(zloF, 20480.f, fmaf(yloF, 128.f, xlo4F)); // exact
        const int totalCh = ZE * FYE * 11;
        const int nIt = (totalCh + 255) >> 8;     // <= 9; overshoot -> clamped addr
        for (int it = 0; it < nIt; ++it) {
            const int k = (it << 8) + tid;
            float kf  = (float)k;
            float zif = floorf(fmaf(kf, RC154, 0.5f * RC154));   // k / 154
            float rem = fmaf(zif, -154.f, kf);                   // k % 154
            float yif = floorf(fmaf(rem, RC11, 0.5f * RC11));    // rem / 11
            float xif = fmaf(yif, -11.f, rem);                   // rem % 11
            float gf  = fmaf(zif, 20480.f, fmaf(yif, 128.f, fmaf(xif, 4.f, gbase)));
            int g = min((int)gf, DHW - 4);                       // tail guard
            __builtin_amdgcn_global_load_lds(
                (const __attribute__((address_space(1))) void*)(sb + g),
                (__attribute__((address_space(3))) void*)(lds + (size_t)(((it << 8) + (wid << 6)) * 4)),
                16, 0, 0);
        }
    }
    __syncthreads();

    const char* Lb = (const char*)lds;

    // packed trilinear from LDS; pair = two consecutive z outputs
    auto triL = [&](int o0, int o1, v2 wx, v2 wy, v2 wz) -> v2 {
        f2 a00 = *(const f2*)(Lb + o0);
        f2 a01 = *(const f2*)(Lb + o0 + ROWB);
        f2 a10 = *(const f2*)(Lb + o0 + SLABB);
        f2 a11 = *(const f2*)(Lb + o0 + SLABB + ROWB);
        f2 b00 = *(const f2*)(Lb + o1);
        f2 b01 = *(const f2*)(Lb + o1 + ROWB);
        f2 b10 = *(const f2*)(Lb + o1 + SLABB);
        f2 b11 = *(const f2*)(Lb + o1 + SLABB + ROWB);
        v2 c00 = {fmaf(a00.y - a00.x, wx.x, a00.x), fmaf(b00.y - b00.x, wx.y, b00.x)};
        v2 c01 = {fmaf(a01.y - a01.x, wx.x, a01.x), fmaf(b01.y - b01.x, wx.y, b01.x)};
        v2 c10 = {fmaf(a10.y - a10.x, wx.x, a10.x), fmaf(b10.y - b10.x, wx.y, b10.x)};
        v2 c11 = {fmaf(a11.y - a11.x, wx.x, a11.x), fmaf(b11.y - b11.x, wx.y, b11.x)};
        v2 c0 = c00 + (c01 - c00) * wy;
        v2 c1 = c10 + (c11 - c10) * wy;
        return c0 + (c1 - c0) * wz;
    };

    if (fits) {
        const v2 dzv = {2.f * pz0, 2.f * pz0};
        const v2 dyv = {2.f * py0, 2.f * py0};
        const v2 dxv = {2.f * px0, 2.f * px0};
        const float hiZ = 127.f - zloF, capZ = 126.f - zloF;
        const float hiY = 159.f - yloF, capY = 158.f - yloF;
        const float hiX = 127.f - xlo4F, capX = 126.f - xlo4F;

        // relative coords for z-pair (z0t+0, z0t+1); exact (lo's are integers)
        v2 az = {izb0 - zloF, izb0 + pz0 - zloF};
        v2 ay = {iyb0 - yloF, iyb0 + py0 - yloF};
        v2 ax = {ixb0 - xlo4F, ixb0 + px0 - xlo4F};

#pragma unroll
        for (int s = 0; s < 4; ++s) {          // pairs (0,1),(2,3),(4,5),(6,7)
            v2 cz, cy, cx, wz, wy, wx;
            if (interior) {
                cz = v2{floorf(az.x), floorf(az.y)};
                cy = v2{floorf(ay.x), floorf(ay.y)};
                cx = v2{floorf(ax.x), floorf(ax.y)};
                wz = az - cz; wy = ay - cy; wx = ax - cx;
            } else {
                v2 azc = {__builtin_amdgcn_fmed3f(az.x, 0.f, hiZ),
                          __builtin_amdgcn_fmed3f(az.y, 0.f, hiZ)};
                v2 ayc = {__builtin_amdgcn_fmed3f(ay.x, 0.f, hiY),
                          __builtin_amdgcn_fmed3f(ay.y, 0.f, hiY)};
                v2 axc = {__builtin_amdgcn_fmed3f(ax.x, 0.f, hiX),
                          __builtin_amdgcn_fmed3f(ax.y, 0.f, hiX)};
                cz = v2{fminf(floorf(azc.x), capZ), fminf(floorf(azc.y), capZ)};
                cy = v2{fminf(floorf(ayc.x), capY), fminf(floorf(ayc.y), capY)};
                cx = v2{fminf(floorf(axc.x), capX), fminf(floorf(axc.y), capX)};
                wz = azc - cz; wy = ayc - cy; wx = axc - cx;
            }
            v2 ob = (cz * (float)FYE + cy) * (float)ROWB + cx * 4.f;  // bytes, exact
            v2 r = triL((int)ob.x, (int)ob.y, wx, wy, wz);
            float* d = dst0 + (s << 1) * HW;
            __builtin_nontemporal_store(r.x, d);
            __builtin_nontemporal_store(r.y, d + HW);
            az += dzv; ay += dyv; ax += dxv;
        }
    } else {
        // direct-gather fallback (rare, >=3.8-sigma affine entry; same math)
        v2 az = {izb0, izb0 + pz0};
        v2 ay = {iyb0, iyb0 + py0};
        v2 ax = {ixb0, ixb0 + px0};
        const v2 dzv = {2.f * pz0, 2.f * pz0};
        const v2 dyv = {2.f * py0, 2.f * py0};
        const v2 dxv = {2.f * px0, 2.f * px0};
#pragma unroll
        for (int s = 0; s < 4; ++s) {
            v2 azc = {__builtin_amdgcn_fmed3f(az.x, 0.f, 127.f),
                      __builtin_amdgcn_fmed3f(az.y, 0.f, 127.f)};
            v2 ayc = {__builtin_amdgcn_fmed3f(ay.x, 0.f, 159.f),
                      __builtin_amdgcn_fmed3f(ay.y, 0.f, 159.f)};
            v2 axc = {__builtin_amdgcn_fmed3f(ax.x, 0.f, 127.f),
                      __builtin_amdgcn_fmed3f(ax.y, 0.f, 127.f)};
            v2 cz = {fminf(floorf(azc.x), 126.f), fminf(floorf(azc.y), 126.f)};
            v2 cy = {fminf(floorf(ayc.x), 158.f), fminf(floorf(ayc.y), 158.f)};
            v2 cx = {fminf(floorf(axc.x), 126.f), fminf(floorf(axc.y), 126.f)};
            v2 wz = azc - cz, wy = ayc - cy, wx = axc - cx;
            auto g1 = [&](float czs, float cys, float cxs, float wxs, float wys, float wzs) -> float {
                int o = (int)fmaf(czs, 20480.f, fmaf(cys, 128.f, cxs));
                const float* p = sb + o;
                f2 v00 = *(const f2*)(p);
                f2 v01 = *(const f2*)(p + WW);
                f2 v10 = *(const f2*)(p + HW);
                f2 v11 = *(const f2*)(p + HW + WW);
                float c00 = fmaf(v00.y - v00.x, wxs, v00.x);
                float c01 = fmaf(v01.y - v01.x, wxs, v01.x);
                float c10 = fmaf(v10.y - v10.x, wxs, v10.x);
                float c11 = fmaf(v11.y - v11.x, wxs, v11.x);
                float c0 = fmaf(c01 - c00, wys, c00);
                float c1 = fmaf(c11 - c10, wys, c10);
                return fmaf(c1 - c0, wzs, c0);
            };
            float* d = dst0 + (s << 1) * HW;
            __builtin_nontemporal_store(g1(cz.x, cy.x, cx.x, wx.x, wy.x, wz.x), d);
            __builtin_nontemporal_store(g1(cz.y, cy.y, cx.y, wx.y, wy.y, wz.y), d + HW);
            az += dzv; ay += dyv; ax += dxv;
        }
    }
}

extern "C" void kernel_launch(void* const* d_in, const int* in_sizes, int n_in,
                              void* d_out, int out_size, void* d_ws, size_t ws_size,
                              hipStream_t stream) {
    const float* src = (const float*)d_in[0];
    const float* aff = (const float*)d_in[1];
    float* out = (float*)d_out;

    st_affine_kernel<<<dim3(NWG), dim3(256), 0, stream>>>(src, aff, out);
}

// Round 16
// 23.846 us; speedup vs baseline: 1.0858x; 1.0458x over previous
//
#include <hip/hip_runtime.h>

#define DD 128
#define HH 160
#define WW 128
#define BB 4
#define HW  20480
#define DHW 2621440

#define TX 32
#define TY 16
#define TZ 8
#define XT 4                     // WW/TX
#define YT 10                    // HH/TY
#define ZT 16                    // DD/TZ
#define NWG (XT * YT * ZT * BB)  // 2560
#define NXCD 8
#define CPX (NWG / NXCD)         // 320

// fixed-shape LDS window (compile-time strides -> immediate DS offsets)
#define FZE   14
#define FYE   21
#define PITCH 44                 // floats per row
#define ROWB  (PITCH * 4)        // 176 B
#define SLABB (FYE * ROWB)       // 3696 B
#define SLABCH (FYE * 11)        // 231 chunks per z-slab (cpr = 11)
#define LDSALLOC 13312           // floats = 53248 B -> 3 blocks/CU (159.7 KB)

typedef float f2 __attribute__((ext_vector_type(2), aligned(4)));
typedef float v2 __attribute__((ext_vector_type(2)));

__global__ __launch_bounds__(256)
void st_affine_kernel(const float* __restrict__ src,
                      const float* __restrict__ aff,
                      float* __restrict__ out) {
    __shared__ float lds[LDSALLOC];

    // XCD-aware bijective swizzle (NWG % 8 == 0)
    const int wgid = blockIdx.x;
    const int lin  = (wgid & (NXCD - 1)) * CPX + (wgid >> 3);
    const int xt = lin & 3;
    const int l2 = lin >> 2;
    const int yt = l2 % YT;
    const int l3 = l2 / YT;
    const int zt = l3 & (ZT - 1);
    const int b  = l3 >> 4;
    const int x0t = xt * TX, y0t = yt * TY, z0t = zt * TZ;

    const float* A = aff + b * 12;   // uniform -> scalar loads
    const float cD = 128.f/127.f, cH = 160.f/159.f, cW = 128.f/127.f;
    const float pz0 = A[0]*cD, pz1 = A[1]*cD, pz2 = A[2]*cD,  pz3 = fmaf(A[3],  cD, -0.5f);
    const float py0 = A[4]*cH, py1 = A[5]*cH, py2 = A[6]*cH,  py3 = fmaf(A[7],  cH, -0.5f);
    const float px0 = A[8]*cW, px1 = A[9]*cW, px2 = A[10]*cW, px3 = fmaf(A[11], cW, -0.5f);

    // ---- EXACT bbox via center +- sum(|coef|*halfext); the 1e-3 slack
    // dominates fp-nesting error (~4e-5), so no +-1 cell margin needed ----
    const float hz = (TZ - 1) * 0.5f, hy = (TY - 1) * 0.5f, hx = (TX - 1) * 0.5f;
    const float ccz = (float)z0t + hz, ccy = (float)y0t + hy, ccx = (float)x0t + hx;
    const float izcn = fmaf(pz0, ccz, fmaf(pz1, ccy, fmaf(pz2, ccx, pz3)));
    const float iycn = fmaf(py0, ccz, fmaf(py1, ccy, fmaf(py2, ccx, py3)));
    const float ixcn = fmaf(px0, ccz, fmaf(px1, ccy, fmaf(px2, ccx, px3)));
    const float rz = fmaf(fabsf(pz0), hz, fmaf(fabsf(pz1), hy, fmaf(fabsf(pz2), hx, 1e-3f)));
    const float ry = fmaf(fabsf(py0), hz, fmaf(fabsf(py1), hy, fmaf(fabsf(py2), hx, 1e-3f)));
    const float rx = fmaf(fabsf(px0), hz, fmaf(fabsf(px1), hy, fmaf(fabsf(px2), hx, 1e-3f)));
    const float mnz = izcn - rz, mxz = izcn + rz;
    const float mny = iycn - ry, mxy = iycn + ry;
    const float mnx = ixcn - rx, mxx = ixcn + rx;

    const bool interior =
        (mnz > 0.02f) && (mxz < 126.98f) &&
        (mny > 0.02f) && (mxy < 158.98f) &&
        (mnx > 0.02f) && (mxx < 126.98f);

    const int zlo = max(0, (int)floorf(__builtin_amdgcn_fmed3f(mnz, 0.f, 127.f)));
    const int ylo = max(0, (int)floorf(__builtin_amdgcn_fmed3f(mny, 0.f, 159.f)));
    const int xlo = max(0, (int)floorf(__builtin_amdgcn_fmed3f(mnx, 0.f, 127.f)));
    const int zhi = min(DD - 2, (int)floorf(__builtin_amdgcn_fmed3f(mxz, 0.f, 127.f)));
    const int yhi = min(HH - 2, (int)floorf(__builtin_amdgcn_fmed3f(mxy, 0.f, 159.f)));
    const int xhi = min(WW - 2, (int)floorf(__builtin_amdgcn_fmed3f(mxx, 0.f, 127.f)));

    const int xlo4 = xlo & ~3;
    const int XE4  = xhi - xlo4 + 2;
    const int YE   = yhi - ylo + 2;
    const int ZE   = zhi - zlo + 2;
    const bool fits = (XE4 <= PITCH) && (YE <= FYE) && (ZE <= FZE);

    const float zloF = (float)zlo, yloF = (float)ylo, xlo4F = (float)xlo4;

    const int tid  = threadIdx.x;
    const int lane = tid & 63;
    const int wid  = tid >> 6;

    // ---- outputs: ONE x per thread (stride-1 -> bank-spread), y-pair
    // (yo, yo+8) packed in v2 lanes, 8-z chain => 16 outputs/thread ----
    const int xq = x0t + (lane & 31);
    const int yo = y0t + (lane >> 5) + (wid << 1);
    const float fx0 = (float)xq, fy = (float)yo, fzb = (float)z0t;

    const float izb0 = fmaf(pz0, fzb, fmaf(pz1, fy, fmaf(pz2, fx0, pz3)));
    const float iyb0 = fmaf(py0, fzb, fmaf(py1, fy, fmaf(py2, fx0, py3)));
    const float ixb0 = fmaf(px0, fzb, fmaf(px1, fy, fmaf(px2, fx0, px3)));
    const float dz8 = 8.f * pz1, dy8 = 8.f * py1, dx8 = 8.f * px1;  // y -> y+8

    const float* sb = src + b * DHW;
    float* dst0 = out + (size_t)(((b * DD + z0t) * HH + yo) * WW + xq);

    // ---- dense full-wave staging into fixed-shape window ----
    if (fits) {
        const float RC231 = 1.f / 231.f, RC11 = 1.f / 11.f;
        const float gbase = fmaf(zloF, 20480.f, fmaf(yloF, 128.f, xlo4F)); // exact
        const int totalCh = ZE * SLABCH;
        const int nIt = (totalCh + 255) >> 8;     // <= 13; overshoot -> clamped addr
        for (int it = 0; it < nIt; ++it) {
            const int k = (it << 8) + tid;
            float kf  = (float)k;
            float zif = floorf(fmaf(kf, RC231, 0.5f * RC231));   // k / 231
            float rem = fmaf(zif, -231.f, kf);                   // k % 231
            float yif = floorf(fmaf(rem, RC11, 0.5f * RC11));    // rem / 11
            float xif = fmaf(yif, -11.f, rem);                   // rem % 11
            float gf  = fmaf(zif, 20480.f, fmaf(yif, 128.f, fmaf(xif, 4.f, gbase)));
            int g = min((int)gf, DHW - 4);                       // tail guard
            __builtin_amdgcn_global_load_lds(
                (const __attribute__((address_space(1))) void*)(sb + g),
                (__attribute__((address_space(3))) void*)(lds + (size_t)(((it << 8) + (wid << 6)) * 4)),
                16, 0, 0);
        }
    }
    __syncthreads();

    const char* Lb = (const char*)lds;

    // packed trilinear from LDS; pair = outputs at (yo, yo+8), same z
    auto triL = [&](int o0, int o1, v2 wx, v2 wy, v2 wz) -> v2 {
        f2 a00 = *(const f2*)(Lb + o0);
        f2 a01 = *(const f2*)(Lb + o0 + ROWB);
        f2 a10 = *(const f2*)(Lb + o0 + SLABB);
        f2 a11 = *(const f2*)(Lb + o0 + SLABB + ROWB);
        f2 b00 = *(const f2*)(Lb + o1);
        f2 b01 = *(const f2*)(Lb + o1 + ROWB);
        f2 b10 = *(const f2*)(Lb + o1 + SLABB);
        f2 b11 = *(const f2*)(Lb + o1 + SLABB + ROWB);
        v2 c00 = {fmaf(a00.y - a00.x, wx.x, a00.x), fmaf(b00.y - b00.x, wx.y, b00.x)};
        v2 c01 = {fmaf(a01.y - a01.x, wx.x, a01.x), fmaf(b01.y - b01.x, wx.y, b01.x)};
        v2 c10 = {fmaf(a10.y - a10.x, wx.x, a10.x), fmaf(b10.y - b10.x, wx.y, b10.x)};
        v2 c11 = {fmaf(a11.y - a11.x, wx.x, a11.x), fmaf(b11.y - b11.x, wx.y, b11.x)};
        v2 c0 = c00 + (c01 - c00) * wy;
        v2 c1 = c10 + (c11 - c10) * wy;
        return c0 + (c1 - c0) * wz;
    };

    if (fits) {
        const v2 dzv = {pz0, pz0}, dyv = {py0, py0}, dxv = {px0, px0};
        const float hiZ = 127.f - zloF, capZ = 126.f - zloF;
        const float hiY = 159.f - yloF, capY = 158.f - yloF;
        const float hiX = 127.f - xlo4F, capX = 126.f - xlo4F;

        // relative coords (exact: lo's are integers -> floor commutes)
        v2 az = {izb0 - zloF, izb0 + dz8 - zloF};
        v2 ay = {iyb0 - yloF, iyb0 + dy8 - yloF};
        v2 ax = {ixb0 - xlo4F, ixb0 + dx8 - xlo4F};

#pragma unroll
        for (int s = 0; s < TZ; ++s) {
            v2 cz, cy, cx, wz, wy, wx;
            if (interior) {
                cz = v2{floorf(az.x), floorf(az.y)};
                cy = v2{floorf(ay.x), floorf(ay.y)};
                cx = v2{floorf(ax.x), floorf(ax.y)};
                wz = az - cz; wy = ay - cy; wx = ax - cx;
            } else {
                v2 azc = {__builtin_amdgcn_fmed3f(az.x, 0.f, hiZ),
                          __builtin_amdgcn_fmed3f(az.y, 0.f, hiZ)};
                v2 ayc = {__builtin_amdgcn_fmed3f(ay.x, 0.f, hiY),
                          __builtin_amdgcn_fmed3f(ay.y, 0.f, hiY)};
                v2 axc = {__builtin_amdgcn_fmed3f(ax.x, 0.f, hiX),
                          __builtin_amdgcn_fmed3f(ax.y, 0.f, hiX)};
                cz = v2{fminf(floorf(azc.x), capZ), fminf(floorf(azc.y), capZ)};
                cy = v2{fminf(floorf(ayc.x), capY), fminf(floorf(ayc.y), capY)};
                cx = v2{fminf(floorf(axc.x), capX), fminf(floorf(axc.y), capX)};
                wz = azc - cz; wy = ayc - cy; wx = axc - cx;
            }
            v2 ob = (cz * (float)FYE + cy) * (float)ROWB + cx * 4.f;  // bytes, exact
            v2 r = triL((int)ob.x, (int)ob.y, wx, wy, wz);
            float* d = dst0 + s * HW;
            __builtin_nontemporal_store(r.x, d);
            __builtin_nontemporal_store(r.y, d + 8 * WW);   // row yo+8
            az += dzv; ay += dyv; ax += dxv;
        }
    } else {
        // direct-gather fallback (rare oversized-bbox batch; same math)
        v2 az = {izb0, izb0 + dz8};
        v2 ay = {iyb0, iyb0 + dy8};
        v2 ax = {ixb0, ixb0 + dx8};
        const v2 dzv = {pz0, pz0}, dyv = {py0, py0}, dxv = {px0, px0};
#pragma unroll
        for (int s = 0; s < TZ; ++s) {
            v2 azc = {__builtin_amdgcn_fmed3f(az.x, 0.f, 127.f),
                      __builtin_amdgcn_fmed3f(az.y, 0.f, 127.f)};
            v2 ayc = {__builtin_amdgcn_fmed3f(ay.x, 0.f, 159.f),
                      __builtin_amdgcn_fmed3f(ay.y, 0.f, 159.f)};
            v2 axc = {__builtin_amdgcn_fmed3f(ax.x, 0.f, 127.f),
                      __builtin_amdgcn_fmed3f(ax.y, 0.f, 127.f)};
            v2 cz = {fminf(floorf(azc.x), 126.f), fminf(floorf(azc.y), 126.f)};
            v2 cy = {fminf(floorf(ayc.x), 158.f), fminf(floorf(ayc.y), 158.f)};
            v2 cx = {fminf(floorf(axc.x), 126.f), fminf(floorf(axc.y), 126.f)};
            v2 wz = azc - cz, wy = ayc - cy, wx = axc - cx;
            auto g1 = [&](float czs, float cys, float cxs, float wxs, float wys, float wzs) -> float {
                int o = (int)fmaf(czs, 20480.f, fmaf(cys, 128.f, cxs));
                const float* p = sb + o;
                f2 v00 = *(const f2*)(p);
                f2 v01 = *(const f2*)(p + WW);
                f2 v10 = *(const f2*)(p + HW);
                f2 v11 = *(const f2*)(p + HW + WW);
                float c00 = fmaf(v00.y - v00.x, wxs, v00.x);
                float c01 = fmaf(v01.y - v01.x, wxs, v01.x);
                float c10 = fmaf(v10.y - v10.x, wxs, v10.x);
                float c11 = fmaf(v11.y - v11.x, wxs, v11.x);
                float c0 = fmaf(c01 - c00, wys, c00);
                float c1 = fmaf(c11 - c10, wys, c10);
                return fmaf(c1 - c0, wzs, c0);
            };
            float* d = dst0 + s * HW;
            __builtin_nontemporal_store(g1(cz.x, cy.x, cx.x, wx.x, wy.x, wz.x), d);
            __builtin_nontemporal_store(g1(cz.y, cy.y, cx.y, wx.y, wy.y, wz.y), d + 8 * WW);
            az += dzv; ay += dyv; ax += dxv;
        }
    }
}

extern "C" void kernel_launch(void* const* d_in, const int* in_sizes, int n_in,
                              void* d_out, int out_size, void* d_ws, size_t ws_size,
                              hipStream_t stream) {
    const float* src = (const float*)d_in[0];
    const float* aff = (const float*)d_in[1];
    float* out = (float*)d_out;

    st_affine_kernel<<<dim3(NWG), dim3(256), 0, stream>>>(src, aff, out);
}